// Round 5
// baseline (252.425 us; speedup 1.0000x reference)
//
#include <hip/hip_runtime.h>
#include <hip/hip_bf16.h>
#include <math.h>

#define BB 2
#define TT 2048
#define DM 1024
#define NH 16
#define HS 64
#define MM (BB*TT)   // 4096

typedef __attribute__((ext_vector_type(8))) short s16x8;
typedef __attribute__((ext_vector_type(4))) float f32x4;

#define MFMA16(a,b,c) __builtin_amdgcn_mfma_f32_16x16x32_bf16((a),(b),(c),0,0,0)

__device__ inline unsigned short f2bf(float f) {   // RNE
    union { float f; unsigned u; } x; x.f = f;
    unsigned r = x.u + 0x7fff + ((x.u >> 16) & 1);
    return (unsigned short)(r >> 16);
}
__device__ inline unsigned short f2bfr(float f) {  // round-half-up (hot path)
    union { float f; unsigned u; } x; x.f = f;
    return (unsigned short)((x.u + 0x8000u) >> 16);
}

__device__ __forceinline__ void gload16(const void* g, void* l) {
    __builtin_amdgcn_global_load_lds(
        (const __attribute__((address_space(1))) unsigned int*)g,
        (__attribute__((address_space(3))) unsigned int*)l, 16, 0, 0);
}

// ---------------------------------------------------------------------------
// Kernel 0: weight convert+transpose.  Wt[n][d] (bf16) from W[h,d,hs] fp32
// (n = h*64+hs), or from Wo[d][n] when wo_mode=1.
// ---------------------------------------------------------------------------
__global__ __launch_bounds__(256) void cvt_w_kernel(
    const float* __restrict__ W0, const float* __restrict__ W1,
    const float* __restrict__ W2, unsigned short* __restrict__ dst, int wo_mode)
{
    __shared__ __align__(16) short Tt[64 * 72];
    const int t = threadIdx.x;
    const int d0 = blockIdx.x * 64;
    const int h  = blockIdx.y;
    const int z  = blockIdx.z;
    const float* W = (z == 0) ? W0 : (z == 1) ? W1 : W2;
    unsigned short* dz = dst + (size_t)z * DM * DM;

    #pragma unroll
    for (int it = 0; it < 16; ++it) {
        int dl = it * 4 + (t >> 6);
        int hs = t & 63;
        float vv = wo_mode ? W[(size_t)(d0 + dl) * DM + h * 64 + hs]
                           : W[(size_t)h * DM * HS + (size_t)(d0 + dl) * HS + hs];
        Tt[hs * 72 + dl] = (short)f2bf(vv);
    }
    __syncthreads();
    int hs = t >> 2, doff = (t & 3) * 16;
    s16x8 r0 = *(s16x8*)&Tt[hs * 72 + doff];
    s16x8 r1 = *(s16x8*)&Tt[hs * 72 + doff + 8];
    unsigned short* op = dz + (size_t)(h * 64 + hs) * DM + d0 + doff;
    *(s16x8*)op = r0;
    *(s16x8*)(op + 8) = r1;
}

// ---------------------------------------------------------------------------
// Kernel 1: Q/K/V projection GEMM, m97-structure (unchanged from round 4).
// ---------------------------------------------------------------------------
__global__ __launch_bounds__(256) void proj_gemm_kernel(
    const float* __restrict__ q, const float* __restrict__ k,
    const float* __restrict__ v, const unsigned short* __restrict__ Wt,
    unsigned short* __restrict__ Qb, unsigned short* __restrict__ Kb,
    unsigned short* __restrict__ Vt)
{
    __shared__ __align__(16) float As[128 * 32];
    __shared__ __align__(16) unsigned short Bs[128 * 32];

    const int tid = threadIdx.x;
    const int l = tid & 63, w = tid >> 6;
    const int wr = w >> 1, wc = w & 1;
    const int g = l >> 4, r16 = l & 15;
    const int z = blockIdx.z;
    const int m0 = blockIdx.y * 128;
    const int n0 = blockIdx.x * 128;

    const float* x = (z == 0) ? q : (z == 1) ? k : v;
    const unsigned short* Wz = Wt + (size_t)z * DM * DM;

    const float* aS[4]; float* aD[4];
    #pragma unroll
    for (int p = 0; p < 4; ++p) {
        int qid = p * 256 + tid;
        int row = qid >> 3, gl = qid & 7;
        int col = ((gl ^ (row & 7)) * 4);
        aS[p] = x + (size_t)(m0 + row) * DM + col;
        aD[p] = As + qid * 4;
    }
    const unsigned short* bS[2]; unsigned short* bD[2];
    #pragma unroll
    for (int p = 0; p < 2; ++p) {
        int qid = p * 256 + tid;
        int row = qid >> 2, gl = qid & 3;
        int col = ((gl ^ ((row >> 1) & 3)) * 8);
        bS[p] = Wz + (size_t)(n0 + row) * DM + col;
        bD[p] = Bs + qid * 8;
    }

    int aoff[4][2], boff[4];
    #pragma unroll
    for (int i = 0; i < 4; ++i) {
        int row = wr * 64 + i * 16 + r16;
        int s = row & 7;
        aoff[i][0] = row * 32 + ((2 * g) ^ s) * 4;
        aoff[i][1] = row * 32 + ((2 * g + 1) ^ s) * 4;
    }
    #pragma unroll
    for (int c = 0; c < 4; ++c) {
        int row = wc * 64 + c * 16 + r16;
        boff[c] = row * 32 + (g ^ ((row >> 1) & 3)) * 8;
    }

    f32x4 acc[4][4];
    #pragma unroll
    for (int i = 0; i < 4; ++i)
        #pragma unroll
        for (int c = 0; c < 4; ++c)
            #pragma unroll
            for (int j = 0; j < 4; ++j) acc[i][c][j] = 0.0f;

    for (int k0 = 0; k0 < DM; k0 += 32) {
        #pragma unroll
        for (int p = 0; p < 4; ++p) gload16(aS[p] + k0, aD[p]);
        #pragma unroll
        for (int p = 0; p < 2; ++p) gload16(bS[p] + k0, bD[p]);
        __syncthreads();

        s16x8 af[4], bf[4];
        #pragma unroll
        for (int i = 0; i < 4; ++i) {
            float4 lo = *(const float4*)&As[aoff[i][0]];
            float4 hi = *(const float4*)&As[aoff[i][1]];
            union { s16x8 v; __hip_bfloat162 h[4]; } cv;
            cv.h[0] = __float22bfloat162_rn(make_float2(lo.x, lo.y));
            cv.h[1] = __float22bfloat162_rn(make_float2(lo.z, lo.w));
            cv.h[2] = __float22bfloat162_rn(make_float2(hi.x, hi.y));
            cv.h[3] = __float22bfloat162_rn(make_float2(hi.z, hi.w));
            af[i] = cv.v;
        }
        #pragma unroll
        for (int c = 0; c < 4; ++c) bf[c] = *(const s16x8*)&Bs[boff[c]];
        #pragma unroll
        for (int i = 0; i < 4; ++i)
            #pragma unroll
            for (int c = 0; c < 4; ++c)
                acc[i][c] = MFMA16(af[i], bf[c], acc[i][c]);
        __syncthreads();
    }

    const int h = (n0 >> 6) + wc;
    if (z != 2) {
        unsigned short* dst = (z == 0) ? Qb : Kb;
        const float sc = (z == 0) ? 0.18033688011112042f : 1.0f;  // 0.125*log2e
        #pragma unroll
        for (int i = 0; i < 4; ++i)
            #pragma unroll
            for (int j = 0; j < 4; ++j) {
                int row = m0 + wr * 64 + i * 16 + g * 4 + j;
                int bb = row >> 11, tt = row & (TT - 1);
                size_t rb = (((size_t)(bb * NH + h)) * TT + tt) * HS;
                #pragma unroll
                for (int c = 0; c < 4; ++c)
                    dst[rb + c * 16 + r16] = f2bf(acc[i][c][j] * sc);
            }
    } else {
        #pragma unroll
        for (int i = 0; i < 4; ++i) {
            int row0 = m0 + wr * 64 + i * 16 + g * 4;
            int bb = row0 >> 11, tt0 = row0 & (TT - 1);
            #pragma unroll
            for (int c = 0; c < 4; ++c) {
                int hs = c * 16 + r16;
                union { unsigned long long u; unsigned short s[4]; } pk;
                #pragma unroll
                for (int j = 0; j < 4; ++j) pk.s[j] = f2bf(acc[i][c][j]);
                *(unsigned long long*)&Vt[(((size_t)(bb * NH + h)) * HS + hs) * TT + tt0] = pk.u;
            }
        }
    }
}

// ---------------------------------------------------------------------------
// Kernel 3: out = Ob @ Wo + bo (fp32 out). (unchanged from round 4)
// ---------------------------------------------------------------------------
__global__ __launch_bounds__(256) void out_gemm_kernel(
    const unsigned short* __restrict__ Ob, const unsigned short* __restrict__ Wot,
    const float* __restrict__ bo, float* __restrict__ out)
{
    __shared__ __align__(16) unsigned short As2[128 * 32];
    __shared__ __align__(16) unsigned short Bs2[128 * 32];

    const int tid = threadIdx.x;
    const int l = tid & 63, w = tid >> 6;
    const int wr = w >> 1, wc = w & 1;
    const int g = l >> 4, r16 = l & 15;
    const int m0 = blockIdx.y * 128;
    const int n0 = blockIdx.x * 128;

    const unsigned short* aS[2]; unsigned short* aD[2];
    const unsigned short* bS[2]; unsigned short* bD[2];
    #pragma unroll
    for (int p = 0; p < 2; ++p) {
        int qid = p * 256 + tid;
        int row = qid >> 2, gl = qid & 3;
        int col = ((gl ^ ((row >> 1) & 3)) * 8);
        aS[p] = Ob + (size_t)(m0 + row) * DM + col;
        aD[p] = As2 + qid * 8;
        bS[p] = Wot + (size_t)(n0 + row) * DM + col;
        bD[p] = Bs2 + qid * 8;
    }

    int aoff[4], boff[4];
    #pragma unroll
    for (int i = 0; i < 4; ++i) {
        int row = wr * 64 + i * 16 + r16;
        aoff[i] = row * 32 + (g ^ ((row >> 1) & 3)) * 8;
    }
    #pragma unroll
    for (int c = 0; c < 4; ++c) {
        int row = wc * 64 + c * 16 + r16;
        boff[c] = row * 32 + (g ^ ((row >> 1) & 3)) * 8;
    }

    f32x4 acc[4][4];
    #pragma unroll
    for (int i = 0; i < 4; ++i)
        #pragma unroll
        for (int c = 0; c < 4; ++c)
            #pragma unroll
            for (int j = 0; j < 4; ++j) acc[i][c][j] = 0.0f;

    for (int k0 = 0; k0 < DM; k0 += 32) {
        #pragma unroll
        for (int p = 0; p < 2; ++p) gload16(aS[p] + k0, aD[p]);
        #pragma unroll
        for (int p = 0; p < 2; ++p) gload16(bS[p] + k0, bD[p]);
        __syncthreads();

        s16x8 af[4], bf[4];
        #pragma unroll
        for (int i = 0; i < 4; ++i) af[i] = *(const s16x8*)&As2[aoff[i]];
        #pragma unroll
        for (int c = 0; c < 4; ++c) bf[c] = *(const s16x8*)&Bs2[boff[c]];
        #pragma unroll
        for (int i = 0; i < 4; ++i)
            #pragma unroll
            for (int c = 0; c < 4; ++c)
                acc[i][c] = MFMA16(af[i], bf[c], acc[i][c]);
        __syncthreads();
    }

    #pragma unroll
    for (int i = 0; i < 4; ++i)
        #pragma unroll
        for (int j = 0; j < 4; ++j) {
            int row = m0 + wr * 64 + i * 16 + g * 4 + j;
            #pragma unroll
            for (int c = 0; c < 4; ++c) {
                int col = n0 + wc * 64 + c * 16 + r16;
                out[(size_t)row * DM + col] = acc[i][c][j] + bo[col];
            }
        }
}

// ---------------------------------------------------------------------------
// Kernel 2: causal flash attention v4 — SWAPPED QK^T (S^T = K·Q^T) so each
// lane owns one q-row; softmax = 7 local max + 2 shuffles (not 32).
// PV computes O^T = mfma(V^T, P). Global loads identical to v3.
// 4096 waves, one 16-row strip each, heavy-first.
// ---------------------------------------------------------------------------
template<bool MASKED>
__device__ __forceinline__ void flash_tile_sw(
    int kv0, int t0, int r16, int g,
    const unsigned short* __restrict__ Kp,
    const unsigned short* __restrict__ Vp,
    short* __restrict__ Pw,
    const s16x8 (&qf)[2],
    float& m_run, float& l_run, f32x4 (&o)[4])
{
    f32x4 sacc[2];
    #pragma unroll
    for (int c = 0; c < 2; ++c)
        #pragma unroll
        for (int j = 0; j < 4; ++j) sacc[c][j] = 0.0f;

    #pragma unroll
    for (int c = 0; c < 2; ++c)
        #pragma unroll
        for (int s = 0; s < 2; ++s) {
            s16x8 kf = *(const s16x8*)(Kp + (size_t)(kv0 + c * 16 + r16) * HS + s * 32 + g * 8);
            sacc[c] = MFMA16(kf, qf[s], sacc[c]);   // S^T[kv][q]
        }

    if (MASKED) {
        #pragma unroll
        for (int c = 0; c < 2; ++c)
            #pragma unroll
            for (int j = 0; j < 4; ++j)
                if (kv0 + c * 16 + g * 4 + j > t0 + r16)
                    sacc[c][j] = -1e30f;
    }

    // per-lane q-row softmax: local 8-max + xor16/xor32 cross-group
    float pm = fmaxf(
        fmaxf(fmaxf(sacc[0][0], sacc[0][1]), fmaxf(sacc[0][2], sacc[0][3])),
        fmaxf(fmaxf(sacc[1][0], sacc[1][1]), fmaxf(sacc[1][2], sacc[1][3])));
    pm = fmaxf(pm, __shfl_xor(pm, 16));
    pm = fmaxf(pm, __shfl_xor(pm, 32));
    float mn = fmaxf(m_run, pm);
    float cr = __builtin_amdgcn_exp2f(m_run - mn);
    m_run = mn;
    float e[2][4];
    #pragma unroll
    for (int c = 0; c < 2; ++c)
        #pragma unroll
        for (int j = 0; j < 4; ++j)
            e[c][j] = __builtin_amdgcn_exp2f(sacc[c][j] - mn);
    float ps = ((e[0][0] + e[0][1]) + (e[0][2] + e[0][3]))
             + ((e[1][0] + e[1][1]) + (e[1][2] + e[1][3]));
    ps += __shfl_xor(ps, 16);
    ps += __shfl_xor(ps, 32);
    l_run = l_run * cr + ps;

    #pragma unroll
    for (int c = 0; c < 4; ++c)
        #pragma unroll
        for (int j = 0; j < 4; ++j) o[c][j] *= cr;

    // P -> LDS [q][kv] (packed u64), read back as B-frag (contiguous b128)
    #pragma unroll
    for (int c = 0; c < 2; ++c) {
        union { unsigned long long u; unsigned short s[4]; } pk;
        #pragma unroll
        for (int j = 0; j < 4; ++j) pk.s[j] = f2bfr(e[c][j]);
        *(unsigned long long*)&Pw[r16 * 36 + c * 16 + g * 4] = pk.u;
    }
    s16x8 pb = *(const s16x8*)&Pw[r16 * 36 + g * 8];

    #pragma unroll
    for (int c = 0; c < 4; ++c) {
        s16x8 vf = *(const s16x8*)(Vp + (size_t)(c * 16 + r16) * TT + kv0 + g * 8);
        o[c] = MFMA16(vf, pb, o[c]);   // O^T[hs][q]
    }
}

__device__ __forceinline__ void flash_strip_sw(
    int t0, int r16, int g,
    const unsigned short* __restrict__ Qp,
    const unsigned short* __restrict__ Kp,
    const unsigned short* __restrict__ Vp,
    unsigned short* __restrict__ Op,
    short* __restrict__ Pw)
{
    s16x8 qf[2];
    #pragma unroll
    for (int s = 0; s < 2; ++s)
        qf[s] = *(const s16x8*)(Qp + (size_t)(t0 + r16) * HS + s * 32 + g * 8);

    float m_run = -INFINITY, l_run = 0.0f;
    f32x4 o[4];
    #pragma unroll
    for (int c = 0; c < 4; ++c)
        #pragma unroll
        for (int j = 0; j < 4; ++j) o[c][j] = 0.0f;

    const int kvF = ((t0 + 1) >> 5) << 5;
    for (int kv0 = 0; kv0 < kvF; kv0 += 32)
        flash_tile_sw<false>(kv0, t0, r16, g, Kp, Vp, Pw, qf, m_run, l_run, o);
    for (int kv0 = kvF; kv0 < t0 + 16; kv0 += 32)
        flash_tile_sw<true>(kv0, t0, r16, g, Kp, Vp, Pw, qf, m_run, l_run, o);

    const float inv = 1.0f / l_run;
    unsigned short* rp = Op + (size_t)(t0 + r16) * DM;
    #pragma unroll
    for (int c = 0; c < 4; ++c) {
        union { unsigned long long u; unsigned short s[4]; } pk;
        #pragma unroll
        for (int j = 0; j < 4; ++j) pk.s[j] = f2bfr(o[c][j] * inv);
        *(unsigned long long*)&rp[c * 16 + g * 4] = pk.u;
    }
}

__global__ __launch_bounds__(256) void flash4_kernel(
    const unsigned short* __restrict__ Qb,
    const unsigned short* __restrict__ Kb,
    const unsigned short* __restrict__ Vt,
    unsigned short* __restrict__ Ob)
{
    __shared__ __align__(16) short Pl[4][16 * 36];

    const int tid = threadIdx.x;
    const int l = tid & 63, w = tid >> 6;
    const int r16 = l & 15, g = l >> 4;

    // 4096 waves, one strip each; heavy strips first; bh = u&31 keeps each
    // XCD on 4 consecutive heads (K+V = 2MB fits per-XCD L2).
    const int u = blockIdx.x * 4 + w;
    const int bh = u & 31;
    const int p  = 127 - (u >> 5);
    const int b = bh >> 4, h = bh & 15;

    const unsigned short* Qp = Qb + (size_t)bh * TT * HS;
    const unsigned short* Kp = Kb + (size_t)bh * TT * HS;
    const unsigned short* Vp = Vt + (size_t)bh * HS * TT;
    unsigned short* Op = Ob + (size_t)b * TT * DM + h * HS;

    flash_strip_sw(16 * p, r16, g, Qp, Kp, Vp, Op, Pl[w]);
}

// ---------------------------------------------------------------------------
extern "C" void kernel_launch(void* const* d_in, const int* in_sizes, int n_in,
                              void* d_out, int out_size, void* d_ws, size_t ws_size,
                              hipStream_t stream) {
    const float* q  = (const float*)d_in[0];
    const float* k  = (const float*)d_in[1];
    const float* v  = (const float*)d_in[2];
    const float* Wq = (const float*)d_in[3];
    const float* Wk = (const float*)d_in[4];
    const float* Wv = (const float*)d_in[5];
    const float* Wo = (const float*)d_in[6];
    const float* bo = (const float*)d_in[7];
    float* out = (float*)d_out;

    const size_t QKV_ELEMS = (size_t)BB * NH * TT * HS;  // 4 Mi elems (8 MB)
    unsigned short* Qb = (unsigned short*)d_ws;
    unsigned short* Kb = Qb + QKV_ELEMS;
    unsigned short* Vt = Kb + QKV_ELEMS;                 // [B,H,HS,T]
    unsigned short* R4 = Vt + QKV_ELEMS;                 // 8 MB shared region
    unsigned short* Wt = R4;                             // Wq/k/v^T (6 MB), pre-flash
    unsigned short* Ob = R4;                             // flash out, overwrites Wt
    unsigned short* Wot = Qb;                            // Wo^T (2 MB), post-flash

    cvt_w_kernel<<<dim3(16, 16, 3), 256, 0, stream>>>(Wq, Wk, Wv, Wt, 0);
    proj_gemm_kernel<<<dim3(8, 32, 3), 256, 0, stream>>>(q, k, v, Wt, Qb, Kb, Vt);
    flash4_kernel<<<dim3(1024), 256, 0, stream>>>(Qb, Kb, Vt, Ob);
    cvt_w_kernel<<<dim3(16, 16, 1), 256, 0, stream>>>(Wo, Wo, Wo, Wot, 1);
    out_gemm_kernel<<<dim3(8, 32), 256, 0, stream>>>(Ob, Wot, bo, out);
}

// Round 6
// 251.596 us; speedup vs baseline: 1.0033x; 1.0033x over previous
//
#include <hip/hip_runtime.h>
#include <hip/hip_bf16.h>
#include <math.h>

#define BB 2
#define TT 2048
#define DM 1024
#define NH 16
#define HS 64
#define MM (BB*TT)   // 4096

typedef __attribute__((ext_vector_type(8))) short s16x8;
typedef __attribute__((ext_vector_type(4))) float f32x4;

#define MFMA16(a,b,c) __builtin_amdgcn_mfma_f32_16x16x32_bf16((a),(b),(c),0,0,0)

__device__ inline unsigned short f2bf(float f) {   // RNE
    union { float f; unsigned u; } x; x.f = f;
    unsigned r = x.u + 0x7fff + ((x.u >> 16) & 1);
    return (unsigned short)(r >> 16);
}
__device__ inline unsigned short f2bfr(float f) {  // round-half-up (hot path)
    union { float f; unsigned u; } x; x.f = f;
    return (unsigned short)((x.u + 0x8000u) >> 16);
}

__device__ __forceinline__ void gload16(const void* g, void* l) {
    __builtin_amdgcn_global_load_lds(
        (const __attribute__((address_space(1))) unsigned int*)g,
        (__attribute__((address_space(3))) unsigned int*)l, 16, 0, 0);
}

// ---------------------------------------------------------------------------
// Kernel 0: weight convert+transpose.  Wt[n][d] (bf16) from W[h,d,hs] fp32
// (n = h*64+hs), or from Wo[d][n] when wo_mode=1.
// ---------------------------------------------------------------------------
__global__ __launch_bounds__(256) void cvt_w_kernel(
    const float* __restrict__ W0, const float* __restrict__ W1,
    const float* __restrict__ W2, unsigned short* __restrict__ dst, int wo_mode)
{
    __shared__ __align__(16) short Tt[64 * 72];
    const int t = threadIdx.x;
    const int d0 = blockIdx.x * 64;
    const int h  = blockIdx.y;
    const int z  = blockIdx.z;
    const float* W = (z == 0) ? W0 : (z == 1) ? W1 : W2;
    unsigned short* dz = dst + (size_t)z * DM * DM;

    #pragma unroll
    for (int it = 0; it < 16; ++it) {
        int dl = it * 4 + (t >> 6);
        int hs = t & 63;
        float vv = wo_mode ? W[(size_t)(d0 + dl) * DM + h * 64 + hs]
                           : W[(size_t)h * DM * HS + (size_t)(d0 + dl) * HS + hs];
        Tt[hs * 72 + dl] = (short)f2bf(vv);
    }
    __syncthreads();
    int hs = t >> 2, doff = (t & 3) * 16;
    s16x8 r0 = *(s16x8*)&Tt[hs * 72 + doff];
    s16x8 r1 = *(s16x8*)&Tt[hs * 72 + doff + 8];
    unsigned short* op = dz + (size_t)(h * 64 + hs) * DM + d0 + doff;
    *(s16x8*)op = r0;
    *(s16x8*)(op + 8) = r1;
}

// ---------------------------------------------------------------------------
// Kernel 1: Q/K/V projection GEMM, m97-structure (unchanged).
// ---------------------------------------------------------------------------
__global__ __launch_bounds__(256) void proj_gemm_kernel(
    const float* __restrict__ q, const float* __restrict__ k,
    const float* __restrict__ v, const unsigned short* __restrict__ Wt,
    unsigned short* __restrict__ Qb, unsigned short* __restrict__ Kb,
    unsigned short* __restrict__ Vt)
{
    __shared__ __align__(16) float As[128 * 32];
    __shared__ __align__(16) unsigned short Bs[128 * 32];

    const int tid = threadIdx.x;
    const int l = tid & 63, w = tid >> 6;
    const int wr = w >> 1, wc = w & 1;
    const int g = l >> 4, r16 = l & 15;
    const int z = blockIdx.z;
    const int m0 = blockIdx.y * 128;
    const int n0 = blockIdx.x * 128;

    const float* x = (z == 0) ? q : (z == 1) ? k : v;
    const unsigned short* Wz = Wt + (size_t)z * DM * DM;

    const float* aS[4]; float* aD[4];
    #pragma unroll
    for (int p = 0; p < 4; ++p) {
        int qid = p * 256 + tid;
        int row = qid >> 3, gl = qid & 7;
        int col = ((gl ^ (row & 7)) * 4);
        aS[p] = x + (size_t)(m0 + row) * DM + col;
        aD[p] = As + qid * 4;
    }
    const unsigned short* bS[2]; unsigned short* bD[2];
    #pragma unroll
    for (int p = 0; p < 2; ++p) {
        int qid = p * 256 + tid;
        int row = qid >> 2, gl = qid & 3;
        int col = ((gl ^ ((row >> 1) & 3)) * 8);
        bS[p] = Wz + (size_t)(n0 + row) * DM + col;
        bD[p] = Bs + qid * 8;
    }

    int aoff[4][2], boff[4];
    #pragma unroll
    for (int i = 0; i < 4; ++i) {
        int row = wr * 64 + i * 16 + r16;
        int s = row & 7;
        aoff[i][0] = row * 32 + ((2 * g) ^ s) * 4;
        aoff[i][1] = row * 32 + ((2 * g + 1) ^ s) * 4;
    }
    #pragma unroll
    for (int c = 0; c < 4; ++c) {
        int row = wc * 64 + c * 16 + r16;
        boff[c] = row * 32 + (g ^ ((row >> 1) & 3)) * 8;
    }

    f32x4 acc[4][4];
    #pragma unroll
    for (int i = 0; i < 4; ++i)
        #pragma unroll
        for (int c = 0; c < 4; ++c)
            #pragma unroll
            for (int j = 0; j < 4; ++j) acc[i][c][j] = 0.0f;

    for (int k0 = 0; k0 < DM; k0 += 32) {
        #pragma unroll
        for (int p = 0; p < 4; ++p) gload16(aS[p] + k0, aD[p]);
        #pragma unroll
        for (int p = 0; p < 2; ++p) gload16(bS[p] + k0, bD[p]);
        __syncthreads();

        s16x8 af[4], bf[4];
        #pragma unroll
        for (int i = 0; i < 4; ++i) {
            float4 lo = *(const float4*)&As[aoff[i][0]];
            float4 hi = *(const float4*)&As[aoff[i][1]];
            union { s16x8 v; __hip_bfloat162 h[4]; } cv;
            cv.h[0] = __float22bfloat162_rn(make_float2(lo.x, lo.y));
            cv.h[1] = __float22bfloat162_rn(make_float2(lo.z, lo.w));
            cv.h[2] = __float22bfloat162_rn(make_float2(hi.x, hi.y));
            cv.h[3] = __float22bfloat162_rn(make_float2(hi.z, hi.w));
            af[i] = cv.v;
        }
        #pragma unroll
        for (int c = 0; c < 4; ++c) bf[c] = *(const s16x8*)&Bs[boff[c]];
        #pragma unroll
        for (int i = 0; i < 4; ++i)
            #pragma unroll
            for (int c = 0; c < 4; ++c)
                acc[i][c] = MFMA16(af[i], bf[c], acc[i][c]);
        __syncthreads();
    }

    const int h = (n0 >> 6) + wc;
    if (z != 2) {
        unsigned short* dst = (z == 0) ? Qb : Kb;
        const float sc = (z == 0) ? 0.18033688011112042f : 1.0f;  // 0.125*log2e
        #pragma unroll
        for (int i = 0; i < 4; ++i)
            #pragma unroll
            for (int j = 0; j < 4; ++j) {
                int row = m0 + wr * 64 + i * 16 + g * 4 + j;
                int bb = row >> 11, tt = row & (TT - 1);
                size_t rb = (((size_t)(bb * NH + h)) * TT + tt) * HS;
                #pragma unroll
                for (int c = 0; c < 4; ++c)
                    dst[rb + c * 16 + r16] = f2bf(acc[i][c][j] * sc);
            }
    } else {
        #pragma unroll
        for (int i = 0; i < 4; ++i) {
            int row0 = m0 + wr * 64 + i * 16 + g * 4;
            int bb = row0 >> 11, tt0 = row0 & (TT - 1);
            #pragma unroll
            for (int c = 0; c < 4; ++c) {
                int hs = c * 16 + r16;
                union { unsigned long long u; unsigned short s[4]; } pk;
                #pragma unroll
                for (int j = 0; j < 4; ++j) pk.s[j] = f2bf(acc[i][c][j]);
                *(unsigned long long*)&Vt[(((size_t)(bb * NH + h)) * HS + hs) * TT + tt0] = pk.u;
            }
        }
    }
}

// ---------------------------------------------------------------------------
// Kernel 3: out = Ob @ Wo + bo (fp32 out). (unchanged)
// ---------------------------------------------------------------------------
__global__ __launch_bounds__(256) void out_gemm_kernel(
    const unsigned short* __restrict__ Ob, const unsigned short* __restrict__ Wot,
    const float* __restrict__ bo, float* __restrict__ out)
{
    __shared__ __align__(16) unsigned short As2[128 * 32];
    __shared__ __align__(16) unsigned short Bs2[128 * 32];

    const int tid = threadIdx.x;
    const int l = tid & 63, w = tid >> 6;
    const int wr = w >> 1, wc = w & 1;
    const int g = l >> 4, r16 = l & 15;
    const int m0 = blockIdx.y * 128;
    const int n0 = blockIdx.x * 128;

    const unsigned short* aS[2]; unsigned short* aD[2];
    const unsigned short* bS[2]; unsigned short* bD[2];
    #pragma unroll
    for (int p = 0; p < 2; ++p) {
        int qid = p * 256 + tid;
        int row = qid >> 2, gl = qid & 3;
        int col = ((gl ^ ((row >> 1) & 3)) * 8);
        aS[p] = Ob + (size_t)(m0 + row) * DM + col;
        aD[p] = As2 + qid * 8;
        bS[p] = Wot + (size_t)(n0 + row) * DM + col;
        bD[p] = Bs2 + qid * 8;
    }

    int aoff[4], boff[4];
    #pragma unroll
    for (int i = 0; i < 4; ++i) {
        int row = wr * 64 + i * 16 + r16;
        aoff[i] = row * 32 + (g ^ ((row >> 1) & 3)) * 8;
    }
    #pragma unroll
    for (int c = 0; c < 4; ++c) {
        int row = wc * 64 + c * 16 + r16;
        boff[c] = row * 32 + (g ^ ((row >> 1) & 3)) * 8;
    }

    f32x4 acc[4][4];
    #pragma unroll
    for (int i = 0; i < 4; ++i)
        #pragma unroll
        for (int c = 0; c < 4; ++c)
            #pragma unroll
            for (int j = 0; j < 4; ++j) acc[i][c][j] = 0.0f;

    for (int k0 = 0; k0 < DM; k0 += 32) {
        #pragma unroll
        for (int p = 0; p < 2; ++p) gload16(aS[p] + k0, aD[p]);
        #pragma unroll
        for (int p = 0; p < 2; ++p) gload16(bS[p] + k0, bD[p]);
        __syncthreads();

        s16x8 af[4], bf[4];
        #pragma unroll
        for (int i = 0; i < 4; ++i) af[i] = *(const s16x8*)&As2[aoff[i]];
        #pragma unroll
        for (int c = 0; c < 4; ++c) bf[c] = *(const s16x8*)&Bs2[boff[c]];
        #pragma unroll
        for (int i = 0; i < 4; ++i)
            #pragma unroll
            for (int c = 0; c < 4; ++c)
                acc[i][c] = MFMA16(af[i], bf[c], acc[i][c]);
        __syncthreads();
    }

    #pragma unroll
    for (int i = 0; i < 4; ++i)
        #pragma unroll
        for (int j = 0; j < 4; ++j) {
            int row = m0 + wr * 64 + i * 16 + g * 4 + j;
            #pragma unroll
            for (int c = 0; c < 4; ++c) {
                int col = n0 + wc * 64 + c * 16 + r16;
                out[(size_t)row * DM + col] = acc[i][c][j] + bo[col];
            }
        }
}

// ---------------------------------------------------------------------------
// Kernel 2: causal flash attention v5 — FIXED-m softmax (m=16 in exp2 domain;
// constant shift cancels in softmax). No running max, no corr-rescale, no
// in-loop shuffles. v3 orientation (proven 0-conflict LDS pattern), KVBLK=64,
// 4096 waves heavy-first.
// ---------------------------------------------------------------------------
template<bool MASKED>
__device__ __forceinline__ void flash_tile64(
    int kv0, int t0, int r16, int g,
    const unsigned short* __restrict__ Kp,
    const unsigned short* __restrict__ Vp,
    short* __restrict__ Pw,
    const s16x8 (&qf)[2],
    float (&l_part)[4], f32x4 (&o)[4])
{
    f32x4 sacc[4];
    #pragma unroll
    for (int c = 0; c < 4; ++c)
        #pragma unroll
        for (int j = 0; j < 4; ++j) sacc[c][j] = 0.0f;

    #pragma unroll
    for (int c = 0; c < 4; ++c)
        #pragma unroll
        for (int s = 0; s < 2; ++s) {
            s16x8 kf = *(const s16x8*)(Kp + (size_t)(kv0 + c * 16 + r16) * HS + s * 32 + g * 8);
            sacc[c] = MFMA16(qf[s], kf, sacc[c]);
        }

    // p = exp2(S - 16); masked cols -> 0. l accumulates per-lane partials.
    #pragma unroll
    for (int c = 0; c < 4; ++c)
        #pragma unroll
        for (int j = 0; j < 4; ++j) {
            float e = __builtin_amdgcn_exp2f(sacc[c][j] - 16.0f);
            if (MASKED)
                e = (kv0 + c * 16 + r16 <= t0 + g * 4 + j) ? e : 0.0f;
            l_part[j] += e;
            Pw[(c >> 1) * 576 + (g * 4 + j) * 36 + (c & 1) * 16 + r16] =
                (short)f2bfr(e);
        }

    s16x8 pa0 = *(const s16x8*)&Pw[r16 * 36 + g * 8];
    s16x8 pa1 = *(const s16x8*)&Pw[576 + r16 * 36 + g * 8];

    #pragma unroll
    for (int c = 0; c < 4; ++c) {
        const unsigned short* vr = Vp + (size_t)(c * 16 + r16) * TT + kv0 + g * 8;
        s16x8 vf0 = *(const s16x8*)vr;
        s16x8 vf1 = *(const s16x8*)(vr + 32);
        o[c] = MFMA16(pa0, vf0, o[c]);
        o[c] = MFMA16(pa1, vf1, o[c]);
    }
}

__device__ __forceinline__ void flash_strip_nm(
    int t0, int r16, int g,
    const unsigned short* __restrict__ Qp,
    const unsigned short* __restrict__ Kp,
    const unsigned short* __restrict__ Vp,
    unsigned short* __restrict__ Op,
    short* __restrict__ Pw)
{
    s16x8 qf[2];
    #pragma unroll
    for (int s = 0; s < 2; ++s)
        qf[s] = *(const s16x8*)(Qp + (size_t)(t0 + r16) * HS + s * 32 + g * 8);

    float l_part[4] = {0.0f, 0.0f, 0.0f, 0.0f};
    f32x4 o[4];
    #pragma unroll
    for (int c = 0; c < 4; ++c)
        #pragma unroll
        for (int j = 0; j < 4; ++j) o[c][j] = 0.0f;

    const int kvF = ((t0 + 1) >> 6) << 6;   // fully-unmasked 64-tiles
    for (int kv0 = 0; kv0 < kvF; kv0 += 64)
        flash_tile64<false>(kv0, t0, r16, g, Kp, Vp, Pw, qf, l_part, o);
    for (int kv0 = kvF; kv0 < t0 + 16; kv0 += 64)
        flash_tile64<true>(kv0, t0, r16, g, Kp, Vp, Pw, qf, l_part, o);

    #pragma unroll
    for (int j = 0; j < 4; ++j) {
        float ls = l_part[j];
        ls += __shfl_xor(ls, 1);
        ls += __shfl_xor(ls, 2);
        ls += __shfl_xor(ls, 4);
        ls += __shfl_xor(ls, 8);
        float inv = 1.0f / ls;
        int t = t0 + g * 4 + j;
        #pragma unroll
        for (int c = 0; c < 4; ++c)
            Op[(size_t)t * DM + c * 16 + r16] = f2bfr(o[c][j] * inv);
    }
}

__global__ __launch_bounds__(256) void flash5_kernel(
    const unsigned short* __restrict__ Qb,
    const unsigned short* __restrict__ Kb,
    const unsigned short* __restrict__ Vt,
    unsigned short* __restrict__ Ob)
{
    __shared__ __align__(16) short Pl[4][2 * 576];   // per-wave 2x[16][36]

    const int tid = threadIdx.x;
    const int l = tid & 63, w = tid >> 6;
    const int r16 = l & 15, g = l >> 4;

    // 4096 waves, one 16-row strip each; heavy strips first; bh = u&31 keeps
    // each XCD on 4 consecutive heads (K+V = 2MB fits per-XCD L2).
    const int u = blockIdx.x * 4 + w;
    const int bh = u & 31;
    const int p  = 127 - (u >> 5);
    const int b = bh >> 4, h = bh & 15;

    const unsigned short* Qp = Qb + (size_t)bh * TT * HS;
    const unsigned short* Kp = Kb + (size_t)bh * TT * HS;
    const unsigned short* Vp = Vt + (size_t)bh * HS * TT;
    unsigned short* Op = Ob + (size_t)b * TT * DM + h * HS;

    flash_strip_nm(16 * p, r16, g, Qp, Kp, Vp, Op, Pl[w]);
}

// ---------------------------------------------------------------------------
extern "C" void kernel_launch(void* const* d_in, const int* in_sizes, int n_in,
                              void* d_out, int out_size, void* d_ws, size_t ws_size,
                              hipStream_t stream) {
    const float* q  = (const float*)d_in[0];
    const float* k  = (const float*)d_in[1];
    const float* v  = (const float*)d_in[2];
    const float* Wq = (const float*)d_in[3];
    const float* Wk = (const float*)d_in[4];
    const float* Wv = (const float*)d_in[5];
    const float* Wo = (const float*)d_in[6];
    const float* bo = (const float*)d_in[7];
    float* out = (float*)d_out;

    const size_t QKV_ELEMS = (size_t)BB * NH * TT * HS;  // 4 Mi elems (8 MB)
    unsigned short* Qb = (unsigned short*)d_ws;
    unsigned short* Kb = Qb + QKV_ELEMS;
    unsigned short* Vt = Kb + QKV_ELEMS;                 // [B,H,HS,T]
    unsigned short* R4 = Vt + QKV_ELEMS;                 // 8 MB shared region
    unsigned short* Wt = R4;                             // Wq/k/v^T (6 MB), pre-flash
    unsigned short* Ob = R4;                             // flash out, overwrites Wt
    unsigned short* Wot = Qb;                            // Wo^T (2 MB), post-flash

    cvt_w_kernel<<<dim3(16, 16, 3), 256, 0, stream>>>(Wq, Wk, Wv, Wt, 0);
    proj_gemm_kernel<<<dim3(8, 32, 3), 256, 0, stream>>>(q, k, v, Wt, Qb, Kb, Vt);
    flash5_kernel<<<dim3(1024), 256, 0, stream>>>(Qb, Kb, Vt, Ob);
    cvt_w_kernel<<<dim3(16, 16, 1), 256, 0, stream>>>(Wo, Wo, Wo, Wot, 1);
    out_gemm_kernel<<<dim3(8, 32), 256, 0, stream>>>(Ob, Wot, bo, out);
}

// Round 7
// 158.773 us; speedup vs baseline: 1.5899x; 1.5846x over previous
//
#include <hip/hip_runtime.h>
#include <hip/hip_bf16.h>
#include <math.h>

#define BB 2
#define TT 2048
#define DM 1024
#define NH 16
#define HS 64
#define MM (BB*TT)   // 4096

typedef __attribute__((ext_vector_type(8))) short s16x8;
typedef __attribute__((ext_vector_type(4))) float f32x4;

#define MFMA16(a,b,c) __builtin_amdgcn_mfma_f32_16x16x32_bf16((a),(b),(c),0,0,0)

__device__ inline unsigned short f2bf(float f) {   // RNE
    union { float f; unsigned u; } x; x.f = f;
    unsigned r = x.u + 0x7fff + ((x.u >> 16) & 1);
    return (unsigned short)(r >> 16);
}
__device__ inline unsigned short f2bfr(float f) {  // round-half-up (hot path)
    union { float f; unsigned u; } x; x.f = f;
    return (unsigned short)((x.u + 0x8000u) >> 16);
}

__device__ __forceinline__ void gload16(const void* g, void* l) {
    __builtin_amdgcn_global_load_lds(
        (const __attribute__((address_space(1))) unsigned int*)g,
        (__attribute__((address_space(3))) unsigned int*)l, 16, 0, 0);
}

// ---------------------------------------------------------------------------
// Kernel 0: weight convert+transpose.  Wt[n][d] (bf16) from W[h,d,hs] fp32
// (n = h*64+hs), or from Wo[d][n] when wo_mode=1.
// ---------------------------------------------------------------------------
__global__ __launch_bounds__(256) void cvt_w_kernel(
    const float* __restrict__ W0, const float* __restrict__ W1,
    const float* __restrict__ W2, unsigned short* __restrict__ dst, int wo_mode)
{
    __shared__ __align__(16) short Tt[64 * 72];
    const int t = threadIdx.x;
    const int d0 = blockIdx.x * 64;
    const int h  = blockIdx.y;
    const int z  = blockIdx.z;
    const float* W = (z == 0) ? W0 : (z == 1) ? W1 : W2;
    unsigned short* dz = dst + (size_t)z * DM * DM;

    #pragma unroll
    for (int it = 0; it < 16; ++it) {
        int dl = it * 4 + (t >> 6);
        int hs = t & 63;
        float vv = wo_mode ? W[(size_t)(d0 + dl) * DM + h * 64 + hs]
                           : W[(size_t)h * DM * HS + (size_t)(d0 + dl) * HS + hs];
        Tt[hs * 72 + dl] = (short)f2bf(vv);
    }
    __syncthreads();
    int hs = t >> 2, doff = (t & 3) * 16;
    s16x8 r0 = *(s16x8*)&Tt[hs * 72 + doff];
    s16x8 r1 = *(s16x8*)&Tt[hs * 72 + doff + 8];
    unsigned short* op = dz + (size_t)(h * 64 + hs) * DM + d0 + doff;
    *(s16x8*)op = r0;
    *(s16x8*)(op + 8) = r1;
}

// ---------------------------------------------------------------------------
// Kernel 1: Q/K/V projection GEMM, m97-structure (unchanged).
// ---------------------------------------------------------------------------
__global__ __launch_bounds__(256) void proj_gemm_kernel(
    const float* __restrict__ q, const float* __restrict__ k,
    const float* __restrict__ v, const unsigned short* __restrict__ Wt,
    unsigned short* __restrict__ Qb, unsigned short* __restrict__ Kb,
    unsigned short* __restrict__ Vt)
{
    __shared__ __align__(16) float As[128 * 32];
    __shared__ __align__(16) unsigned short Bs[128 * 32];

    const int tid = threadIdx.x;
    const int l = tid & 63, w = tid >> 6;
    const int wr = w >> 1, wc = w & 1;
    const int g = l >> 4, r16 = l & 15;
    const int z = blockIdx.z;
    const int m0 = blockIdx.y * 128;
    const int n0 = blockIdx.x * 128;

    const float* x = (z == 0) ? q : (z == 1) ? k : v;
    const unsigned short* Wz = Wt + (size_t)z * DM * DM;

    const float* aS[4]; float* aD[4];
    #pragma unroll
    for (int p = 0; p < 4; ++p) {
        int qid = p * 256 + tid;
        int row = qid >> 3, gl = qid & 7;
        int col = ((gl ^ (row & 7)) * 4);
        aS[p] = x + (size_t)(m0 + row) * DM + col;
        aD[p] = As + qid * 4;
    }
    const unsigned short* bS[2]; unsigned short* bD[2];
    #pragma unroll
    for (int p = 0; p < 2; ++p) {
        int qid = p * 256 + tid;
        int row = qid >> 2, gl = qid & 3;
        int col = ((gl ^ ((row >> 1) & 3)) * 8);
        bS[p] = Wz + (size_t)(n0 + row) * DM + col;
        bD[p] = Bs + qid * 8;
    }

    int aoff[4][2], boff[4];
    #pragma unroll
    for (int i = 0; i < 4; ++i) {
        int row = wr * 64 + i * 16 + r16;
        int s = row & 7;
        aoff[i][0] = row * 32 + ((2 * g) ^ s) * 4;
        aoff[i][1] = row * 32 + ((2 * g + 1) ^ s) * 4;
    }
    #pragma unroll
    for (int c = 0; c < 4; ++c) {
        int row = wc * 64 + c * 16 + r16;
        boff[c] = row * 32 + (g ^ ((row >> 1) & 3)) * 8;
    }

    f32x4 acc[4][4];
    #pragma unroll
    for (int i = 0; i < 4; ++i)
        #pragma unroll
        for (int c = 0; c < 4; ++c)
            #pragma unroll
            for (int j = 0; j < 4; ++j) acc[i][c][j] = 0.0f;

    for (int k0 = 0; k0 < DM; k0 += 32) {
        #pragma unroll
        for (int p = 0; p < 4; ++p) gload16(aS[p] + k0, aD[p]);
        #pragma unroll
        for (int p = 0; p < 2; ++p) gload16(bS[p] + k0, bD[p]);
        __syncthreads();

        s16x8 af[4], bf[4];
        #pragma unroll
        for (int i = 0; i < 4; ++i) {
            float4 lo = *(const float4*)&As[aoff[i][0]];
            float4 hi = *(const float4*)&As[aoff[i][1]];
            union { s16x8 v; __hip_bfloat162 h[4]; } cv;
            cv.h[0] = __float22bfloat162_rn(make_float2(lo.x, lo.y));
            cv.h[1] = __float22bfloat162_rn(make_float2(lo.z, lo.w));
            cv.h[2] = __float22bfloat162_rn(make_float2(hi.x, hi.y));
            cv.h[3] = __float22bfloat162_rn(make_float2(hi.z, hi.w));
            af[i] = cv.v;
        }
        #pragma unroll
        for (int c = 0; c < 4; ++c) bf[c] = *(const s16x8*)&Bs[boff[c]];
        #pragma unroll
        for (int i = 0; i < 4; ++i)
            #pragma unroll
            for (int c = 0; c < 4; ++c)
                acc[i][c] = MFMA16(af[i], bf[c], acc[i][c]);
        __syncthreads();
    }

    const int h = (n0 >> 6) + wc;
    if (z != 2) {
        unsigned short* dst = (z == 0) ? Qb : Kb;
        const float sc = (z == 0) ? 0.18033688011112042f : 1.0f;  // 0.125*log2e
        #pragma unroll
        for (int i = 0; i < 4; ++i)
            #pragma unroll
            for (int j = 0; j < 4; ++j) {
                int row = m0 + wr * 64 + i * 16 + g * 4 + j;
                int bb = row >> 11, tt = row & (TT - 1);
                size_t rb = (((size_t)(bb * NH + h)) * TT + tt) * HS;
                #pragma unroll
                for (int c = 0; c < 4; ++c)
                    dst[rb + c * 16 + r16] = f2bf(acc[i][c][j] * sc);
            }
    } else {
        #pragma unroll
        for (int i = 0; i < 4; ++i) {
            int row0 = m0 + wr * 64 + i * 16 + g * 4;
            int bb = row0 >> 11, tt0 = row0 & (TT - 1);
            #pragma unroll
            for (int c = 0; c < 4; ++c) {
                int hs = c * 16 + r16;
                union { unsigned long long u; unsigned short s[4]; } pk;
                #pragma unroll
                for (int j = 0; j < 4; ++j) pk.s[j] = f2bf(acc[i][c][j]);
                *(unsigned long long*)&Vt[(((size_t)(bb * NH + h)) * HS + hs) * TT + tt0] = pk.u;
            }
        }
    }
}

// ---------------------------------------------------------------------------
// Kernel 3: out = Ob @ Wo + bo (fp32 out). (unchanged)
// ---------------------------------------------------------------------------
__global__ __launch_bounds__(256) void out_gemm_kernel(
    const unsigned short* __restrict__ Ob, const unsigned short* __restrict__ Wot,
    const float* __restrict__ bo, float* __restrict__ out)
{
    __shared__ __align__(16) unsigned short As2[128 * 32];
    __shared__ __align__(16) unsigned short Bs2[128 * 32];

    const int tid = threadIdx.x;
    const int l = tid & 63, w = tid >> 6;
    const int wr = w >> 1, wc = w & 1;
    const int g = l >> 4, r16 = l & 15;
    const int m0 = blockIdx.y * 128;
    const int n0 = blockIdx.x * 128;

    const unsigned short* aS[2]; unsigned short* aD[2];
    const unsigned short* bS[2]; unsigned short* bD[2];
    #pragma unroll
    for (int p = 0; p < 2; ++p) {
        int qid = p * 256 + tid;
        int row = qid >> 2, gl = qid & 3;
        int col = ((gl ^ ((row >> 1) & 3)) * 8);
        aS[p] = Ob + (size_t)(m0 + row) * DM + col;
        aD[p] = As2 + qid * 8;
        bS[p] = Wot + (size_t)(n0 + row) * DM + col;
        bD[p] = Bs2 + qid * 8;
    }

    int aoff[4], boff[4];
    #pragma unroll
    for (int i = 0; i < 4; ++i) {
        int row = wr * 64 + i * 16 + r16;
        aoff[i] = row * 32 + (g ^ ((row >> 1) & 3)) * 8;
    }
    #pragma unroll
    for (int c = 0; c < 4; ++c) {
        int row = wc * 64 + c * 16 + r16;
        boff[c] = row * 32 + (g ^ ((row >> 1) & 3)) * 8;
    }

    f32x4 acc[4][4];
    #pragma unroll
    for (int i = 0; i < 4; ++i)
        #pragma unroll
        for (int c = 0; c < 4; ++c)
            #pragma unroll
            for (int j = 0; j < 4; ++j) acc[i][c][j] = 0.0f;

    for (int k0 = 0; k0 < DM; k0 += 32) {
        #pragma unroll
        for (int p = 0; p < 2; ++p) gload16(aS[p] + k0, aD[p]);
        #pragma unroll
        for (int p = 0; p < 2; ++p) gload16(bS[p] + k0, bD[p]);
        __syncthreads();

        s16x8 af[4], bf[4];
        #pragma unroll
        for (int i = 0; i < 4; ++i) af[i] = *(const s16x8*)&As2[aoff[i]];
        #pragma unroll
        for (int c = 0; c < 4; ++c) bf[c] = *(const s16x8*)&Bs2[boff[c]];
        #pragma unroll
        for (int i = 0; i < 4; ++i)
            #pragma unroll
            for (int c = 0; c < 4; ++c)
                acc[i][c] = MFMA16(af[i], bf[c], acc[i][c]);
        __syncthreads();
    }

    #pragma unroll
    for (int i = 0; i < 4; ++i)
        #pragma unroll
        for (int j = 0; j < 4; ++j) {
            int row = m0 + wr * 64 + i * 16 + g * 4 + j;
            #pragma unroll
            for (int c = 0; c < 4; ++c) {
                int col = n0 + wc * 64 + c * 16 + r16;
                out[(size_t)row * DM + col] = acc[i][c][j] + bo[col];
            }
        }
}

// ---------------------------------------------------------------------------
// Kernel 2: causal flash attention v6 — block-cooperative LDS staging.
// Block = 4 waves = (bh, 64-row q-chunk). K/V 64x64 tiles staged via
// global_load_lds (swizzled source, linear dest), double-buffered with
// counted vmcnt + raw s_barrier. Fixed-m softmax (v5). Wave w owns rows
// qc*64 + w*16 .. +15; last tile masked (chunks c<=w live).
// ---------------------------------------------------------------------------
template<bool MASKED>
__device__ __forceinline__ void ftile6(
    int kv0, int t0, int r16, int g,
    const unsigned short* __restrict__ Kl,
    const unsigned short* __restrict__ Vl,
    short* __restrict__ Pw,
    const s16x8 (&qf)[2],
    float (&l_part)[4], f32x4 (&o)[4])
{
    const int rs = r16 & 7;
    float pe[4][4];
    #pragma unroll
    for (int c = 0; c < 4; ++c) {
        if (!MASKED || (kv0 + c * 16 <= t0 + 15)) {
            f32x4 s0;
            #pragma unroll
            for (int j = 0; j < 4; ++j) s0[j] = 0.0f;
            const int base = (c * 16 + r16) * 64;
            s16x8 kf0 = *(const s16x8*)&Kl[base + ((g ^ rs) * 8)];
            s16x8 kf1 = *(const s16x8*)&Kl[base + (((4 + g) ^ rs) * 8)];
            s0 = MFMA16(qf[0], kf0, s0);
            s0 = MFMA16(qf[1], kf1, s0);
            #pragma unroll
            for (int j = 0; j < 4; ++j) {
                float e = __builtin_amdgcn_exp2f(s0[j] - 16.0f);
                if (MASKED)
                    e = (kv0 + c * 16 + r16 <= t0 + g * 4 + j) ? e : 0.0f;
                pe[c][j] = e;
                l_part[j] += e;
            }
        } else {
            #pragma unroll
            for (int j = 0; j < 4; ++j) pe[c][j] = 0.0f;
        }
    }

    // P half 0 (kv cols 0..31) -> LDS -> A-frag, PV s=0
    #pragma unroll
    for (int c = 0; c < 2; ++c)
        #pragma unroll
        for (int j = 0; j < 4; ++j)
            Pw[(g * 4 + j) * 36 + c * 16 + r16] = (short)f2bfr(pe[c][j]);
    s16x8 pa0 = *(const s16x8*)&Pw[r16 * 36 + g * 8];
    #pragma unroll
    for (int c = 0; c < 4; ++c) {
        s16x8 vf = *(const s16x8*)&Vl[(c * 16 + r16) * 64 + ((g ^ rs) * 8)];
        o[c] = MFMA16(pa0, vf, o[c]);
    }

    // P half 1 (kv cols 32..63), skipped when wholly masked
    if (!MASKED || (kv0 + 32 <= t0 + 15)) {
        #pragma unroll
        for (int c = 0; c < 2; ++c)
            #pragma unroll
            for (int j = 0; j < 4; ++j)
                Pw[(g * 4 + j) * 36 + c * 16 + r16] = (short)f2bfr(pe[2 + c][j]);
        s16x8 pa1 = *(const s16x8*)&Pw[r16 * 36 + g * 8];
        #pragma unroll
        for (int c = 0; c < 4; ++c) {
            s16x8 vf = *(const s16x8*)&Vl[(c * 16 + r16) * 64 + (((4 + g) ^ rs) * 8)];
            o[c] = MFMA16(pa1, vf, o[c]);
        }
    }
}

__global__ __launch_bounds__(256) void flash6_kernel(
    const unsigned short* __restrict__ Qb,
    const unsigned short* __restrict__ Kb,
    const unsigned short* __restrict__ Vt,
    unsigned short* __restrict__ Ob)
{
    __shared__ __align__(16) unsigned short Kls[2][4096];  // [64][64] x dbuf
    __shared__ __align__(16) unsigned short Vls[2][4096];
    __shared__ __align__(16) short Pl[4][576];             // per-wave [16][36]

    const int tid = threadIdx.x;
    const int l = tid & 63, w = tid >> 6;
    const int r16 = l & 15, g = l >> 4;

    // bh = bid&31 -> XCD x owns heads {x, x+8, x+16, x+24} (K+V 2MB in L2).
    // qc arranged so the 4 blocks co-resident on a CU (bid, bid+256, ...)
    // have qc summing to 62 -> uniform 66 tiles per CU.
    const int bid = blockIdx.x;
    const int bh = bid & 31;
    const int jj = (bid >> 5) & 7;
    const int ii = bid >> 8;
    const int qc = ii * 8 + ((ii & 1) ? (7 - jj) : jj);
    const int numt = qc + 1;
    const int b = bh >> 4, h = bh & 15;

    const unsigned short* Qp = Qb + (size_t)bh * TT * HS;
    const unsigned short* Kp = Kb + (size_t)bh * TT * HS;
    const unsigned short* Vp = Vt + (size_t)bh * HS * TT;
    unsigned short* Op = Ob + (size_t)b * TT * DM + h * HS;
    short* Pw = Pl[w];

    const int t0 = qc * 64 + w * 16;

    // per-thread staging constants (swizzled global source, linear LDS dest)
    const int srow0 = tid >> 3, c8 = tid & 7;
    const int srow1 = 32 + srow0;
    const unsigned short* kS0 = Kp + srow0 * HS + ((c8 ^ (srow0 & 7)) * 8);
    const unsigned short* kS1 = Kp + srow1 * HS + ((c8 ^ (srow1 & 7)) * 8);
    const unsigned short* vS0 = Vp + (size_t)srow0 * TT + ((c8 ^ (srow0 & 7)) * 8);
    const unsigned short* vS1 = Vp + (size_t)srow1 * TT + ((c8 ^ (srow1 & 7)) * 8);
    const int d0 = tid * 8, d1 = 2048 + tid * 8;

    // Q fragments for this wave's strip
    s16x8 qf[2];
    #pragma unroll
    for (int s = 0; s < 2; ++s)
        qf[s] = *(const s16x8*)(Qp + (size_t)(t0 + r16) * HS + s * 32 + g * 8);

    float l_part[4] = {0.0f, 0.0f, 0.0f, 0.0f};
    f32x4 o[4];
    #pragma unroll
    for (int c = 0; c < 4; ++c)
        #pragma unroll
        for (int j = 0; j < 4; ++j) o[c][j] = 0.0f;

    #define STAGE(buf, kv0_) do {                                   \
        gload16(kS0 + (size_t)(kv0_) * HS, &Kls[(buf)][d0]);        \
        gload16(kS1 + (size_t)(kv0_) * HS, &Kls[(buf)][d1]);        \
        gload16(vS0 + (kv0_), &Vls[(buf)][d0]);                     \
        gload16(vS1 + (kv0_), &Vls[(buf)][d1]);                     \
    } while (0)

    STAGE(0, 0);
    for (int t = 0; t < numt - 1; ++t) {
        STAGE((t + 1) & 1, (t + 1) * 64);
        asm volatile("s_waitcnt vmcnt(4)" ::: "memory");
        __builtin_amdgcn_sched_barrier(0);
        __builtin_amdgcn_s_barrier();
        ftile6<false>(t * 64, t0, r16, g, &Kls[t & 1][0], &Vls[t & 1][0],
                      Pw, qf, l_part, o);
        __builtin_amdgcn_s_barrier();
    }
    asm volatile("s_waitcnt vmcnt(0)" ::: "memory");
    __builtin_amdgcn_sched_barrier(0);
    __builtin_amdgcn_s_barrier();
    ftile6<true>((numt - 1) * 64, t0, r16, g,
                 &Kls[(numt - 1) & 1][0], &Vls[(numt - 1) & 1][0],
                 Pw, qf, l_part, o);
    #undef STAGE

    #pragma unroll
    for (int j = 0; j < 4; ++j) {
        float ls = l_part[j];
        ls += __shfl_xor(ls, 1);
        ls += __shfl_xor(ls, 2);
        ls += __shfl_xor(ls, 4);
        ls += __shfl_xor(ls, 8);
        float inv = 1.0f / ls;
        int t = t0 + g * 4 + j;
        #pragma unroll
        for (int c = 0; c < 4; ++c)
            Op[(size_t)t * DM + c * 16 + r16] = f2bfr(o[c][j] * inv);
    }
}

// ---------------------------------------------------------------------------
extern "C" void kernel_launch(void* const* d_in, const int* in_sizes, int n_in,
                              void* d_out, int out_size, void* d_ws, size_t ws_size,
                              hipStream_t stream) {
    const float* q  = (const float*)d_in[0];
    const float* k  = (const float*)d_in[1];
    const float* v  = (const float*)d_in[2];
    const float* Wq = (const float*)d_in[3];
    const float* Wk = (const float*)d_in[4];
    const float* Wv = (const float*)d_in[5];
    const float* Wo = (const float*)d_in[6];
    const float* bo = (const float*)d_in[7];
    float* out = (float*)d_out;

    const size_t QKV_ELEMS = (size_t)BB * NH * TT * HS;  // 4 Mi elems (8 MB)
    unsigned short* Qb = (unsigned short*)d_ws;
    unsigned short* Kb = Qb + QKV_ELEMS;
    unsigned short* Vt = Kb + QKV_ELEMS;                 // [B,H,HS,T]
    unsigned short* R4 = Vt + QKV_ELEMS;                 // 8 MB shared region
    unsigned short* Wt = R4;                             // Wq/k/v^T (6 MB), pre-flash
    unsigned short* Ob = R4;                             // flash out, overwrites Wt
    unsigned short* Wot = Qb;                            // Wo^T (2 MB), post-flash

    cvt_w_kernel<<<dim3(16, 16, 3), 256, 0, stream>>>(Wq, Wk, Wv, Wt, 0);
    proj_gemm_kernel<<<dim3(8, 32, 3), 256, 0, stream>>>(q, k, v, Wt, Qb, Kb, Vt);
    flash6_kernel<<<dim3(1024), 256, 0, stream>>>(Qb, Kb, Vt, Ob);
    cvt_w_kernel<<<dim3(16, 16, 1), 256, 0, stream>>>(Wo, Wo, Wo, Wot, 1);
    out_gemm_kernel<<<dim3(8, 32), 256, 0, stream>>>(Ob, Wot, bo, out);
}

// Round 8
// 133.598 us; speedup vs baseline: 1.8894x; 1.1884x over previous
//
#include <hip/hip_runtime.h>
#include <hip/hip_bf16.h>
#include <math.h>

#define BB 2
#define TT 2048
#define DM 1024
#define NH 16
#define HS 64
#define MM (BB*TT)   // 4096

typedef __attribute__((ext_vector_type(8))) short s16x8;
typedef __attribute__((ext_vector_type(4))) float f32x4;

#define MFMA16(a,b,c) __builtin_amdgcn_mfma_f32_16x16x32_bf16((a),(b),(c),0,0,0)

__device__ inline unsigned short f2bf(float f) {   // RNE
    union { float f; unsigned u; } x; x.f = f;
    unsigned r = x.u + 0x7fff + ((x.u >> 16) & 1);
    return (unsigned short)(r >> 16);
}
__device__ inline unsigned short f2bfr(float f) {  // round-half-up (hot path)
    union { float f; unsigned u; } x; x.f = f;
    return (unsigned short)((x.u + 0x8000u) >> 16);
}

__device__ __forceinline__ void gload16(const void* g, void* l) {
    __builtin_amdgcn_global_load_lds(
        (const __attribute__((address_space(1))) unsigned int*)g,
        (__attribute__((address_space(3))) unsigned int*)l, 16, 0, 0);
}

// ---------------------------------------------------------------------------
// Kernel 0: weight convert+transpose.  Wt[n][d] (bf16) from W[h,d,hs] fp32
// (n = h*64+hs), or from Wo[d][n] when wo_mode=1.
// ---------------------------------------------------------------------------
__global__ __launch_bounds__(256) void cvt_w_kernel(
    const float* __restrict__ W0, const float* __restrict__ W1,
    const float* __restrict__ W2, unsigned short* __restrict__ dst, int wo_mode)
{
    __shared__ __align__(16) short Tt[64 * 72];
    const int t = threadIdx.x;
    const int d0 = blockIdx.x * 64;
    const int h  = blockIdx.y;
    const int z  = blockIdx.z;
    const float* W = (z == 0) ? W0 : (z == 1) ? W1 : W2;
    unsigned short* dz = dst + (size_t)z * DM * DM;

    #pragma unroll
    for (int it = 0; it < 16; ++it) {
        int dl = it * 4 + (t >> 6);
        int hs = t & 63;
        float vv = wo_mode ? W[(size_t)(d0 + dl) * DM + h * 64 + hs]
                           : W[(size_t)h * DM * HS + (size_t)(d0 + dl) * HS + hs];
        Tt[hs * 72 + dl] = (short)f2bf(vv);
    }
    __syncthreads();
    int hs = t >> 2, doff = (t & 3) * 16;
    s16x8 r0 = *(s16x8*)&Tt[hs * 72 + doff];
    s16x8 r1 = *(s16x8*)&Tt[hs * 72 + doff + 8];
    unsigned short* op = dz + (size_t)(h * 64 + hs) * DM + d0 + doff;
    *(s16x8*)op = r0;
    *(s16x8*)(op + 8) = r1;
}

// ---------------------------------------------------------------------------
// Kernel 1: Q/K/V projection GEMM v2.
// 128x128 tile, BK=32, 4 waves. XCD-ownership mapping: xcd=bid&7 owns 4
// contiguous m-panels per z (A-panel fetched by ONE XCD only). Double-
// buffered LDS staging with counted vmcnt(6) + raw s_barrier (2-phase).
// ---------------------------------------------------------------------------
__global__ __launch_bounds__(256) void proj_gemm_kernel(
    const float* __restrict__ q, const float* __restrict__ k,
    const float* __restrict__ v, const unsigned short* __restrict__ Wt,
    unsigned short* __restrict__ Qb, unsigned short* __restrict__ Kb,
    unsigned short* __restrict__ Vt)
{
    __shared__ __align__(16) float As[2][128 * 32];           // 32 KB
    __shared__ __align__(16) unsigned short Bs[2][128 * 32];  // 16 KB

    const int tid = threadIdx.x;
    const int l = tid & 63, w = tid >> 6;
    const int wr = w >> 1, wc = w & 1;
    const int g = l >> 4, r16 = l & 15;

    // bid -> (z, m-panel, n-panel): XCD owns m-panels {xcd*4..xcd*4+3} per z.
    const int bid = blockIdx.x;
    const int xcd = bid & 7, u = bid >> 3;
    const int z = u >> 5, vv = u & 31;
    const int n0 = (vv >> 2) * 128;
    const int m0 = (xcd * 4 + (vv & 3)) * 128;

    const float* x = (z == 0) ? q : (z == 1) ? k : v;
    const unsigned short* Wz = Wt + (size_t)z * DM * DM;

    // staging addresses (A: 1024 16B-chunks in 4 passes; B: 512 in 2)
    const float* aS[4]; int aDof[4];
    #pragma unroll
    for (int p = 0; p < 4; ++p) {
        int qid = p * 256 + tid;
        int row = qid >> 3, gl = qid & 7;
        int col = ((gl ^ (row & 7)) * 4);
        aS[p] = x + (size_t)(m0 + row) * DM + col;
        aDof[p] = qid * 4;
    }
    const unsigned short* bS[2]; int bDof[2];
    #pragma unroll
    for (int p = 0; p < 2; ++p) {
        int qid = p * 256 + tid;
        int row = qid >> 2, gl = qid & 3;
        int col = ((gl ^ ((row >> 1) & 3)) * 8);
        bS[p] = Wz + (size_t)(n0 + row) * DM + col;
        bDof[p] = qid * 8;
    }

    // fragment LDS offsets (k0-invariant, within one buffer)
    int aoff[4][2], boff[4];
    #pragma unroll
    for (int i = 0; i < 4; ++i) {
        int row = wr * 64 + i * 16 + r16;
        int s = row & 7;
        aoff[i][0] = row * 32 + ((2 * g) ^ s) * 4;
        aoff[i][1] = row * 32 + ((2 * g + 1) ^ s) * 4;
    }
    #pragma unroll
    for (int c = 0; c < 4; ++c) {
        int row = wc * 64 + c * 16 + r16;
        boff[c] = row * 32 + (g ^ ((row >> 1) & 3)) * 8;
    }

    f32x4 acc[4][4];
    #pragma unroll
    for (int i = 0; i < 4; ++i)
        #pragma unroll
        for (int c = 0; c < 4; ++c)
            #pragma unroll
            for (int j = 0; j < 4; ++j) acc[i][c][j] = 0.0f;

    #define PSTAGE(buf, k0_) do {                                        \
        _Pragma("unroll")                                                \
        for (int p = 0; p < 4; ++p)                                      \
            gload16(aS[p] + (k0_), &As[(buf)][aDof[p]]);                 \
        _Pragma("unroll")                                                \
        for (int p = 0; p < 2; ++p)                                      \
            gload16(bS[p] + (k0_), &Bs[(buf)][bDof[p]]);                 \
    } while (0)

    #define PCOMPUTE(buf) do {                                           \
        s16x8 af[4], bf[4];                                              \
        _Pragma("unroll")                                                \
        for (int i = 0; i < 4; ++i) {                                    \
            float4 lo = *(const float4*)&As[(buf)][aoff[i][0]];          \
            float4 hi = *(const float4*)&As[(buf)][aoff[i][1]];          \
            union { s16x8 v; __hip_bfloat162 h[4]; } cv;                 \
            cv.h[0] = __float22bfloat162_rn(make_float2(lo.x, lo.y));    \
            cv.h[1] = __float22bfloat162_rn(make_float2(lo.z, lo.w));    \
            cv.h[2] = __float22bfloat162_rn(make_float2(hi.x, hi.y));    \
            cv.h[3] = __float22bfloat162_rn(make_float2(hi.z, hi.w));    \
            af[i] = cv.v;                                                \
        }                                                                \
        _Pragma("unroll")                                                \
        for (int c = 0; c < 4; ++c) bf[c] = *(const s16x8*)&Bs[(buf)][boff[c]]; \
        _Pragma("unroll")                                                \
        for (int i = 0; i < 4; ++i)                                      \
            _Pragma("unroll")                                            \
            for (int c = 0; c < 4; ++c)                                  \
                acc[i][c] = MFMA16(af[i], bf[c], acc[i][c]);             \
    } while (0)

    PSTAGE(0, 0);
    for (int t = 0; t < 31; ++t) {
        PSTAGE((t + 1) & 1, (t + 1) * 32);
        asm volatile("s_waitcnt vmcnt(6)" ::: "memory");
        __builtin_amdgcn_sched_barrier(0);
        __builtin_amdgcn_s_barrier();
        PCOMPUTE(t & 1);
        __builtin_amdgcn_s_barrier();
    }
    asm volatile("s_waitcnt vmcnt(0)" ::: "memory");
    __builtin_amdgcn_sched_barrier(0);
    __builtin_amdgcn_s_barrier();
    PCOMPUTE(1);
    #undef PSTAGE
    #undef PCOMPUTE

    const int h = (n0 >> 6) + wc;
    if (z != 2) {
        unsigned short* dst = (z == 0) ? Qb : Kb;
        const float sc = (z == 0) ? 0.18033688011112042f : 1.0f;  // 0.125*log2e
        #pragma unroll
        for (int i = 0; i < 4; ++i)
            #pragma unroll
            for (int j = 0; j < 4; ++j) {
                int row = m0 + wr * 64 + i * 16 + g * 4 + j;
                int bb = row >> 11, tt = row & (TT - 1);
                size_t rb = (((size_t)(bb * NH + h)) * TT + tt) * HS;
                #pragma unroll
                for (int c = 0; c < 4; ++c)
                    dst[rb + c * 16 + r16] = f2bf(acc[i][c][j] * sc);
            }
    } else {
        #pragma unroll
        for (int i = 0; i < 4; ++i) {
            int row0 = m0 + wr * 64 + i * 16 + g * 4;
            int bb = row0 >> 11, tt0 = row0 & (TT - 1);
            #pragma unroll
            for (int c = 0; c < 4; ++c) {
                int hs = c * 16 + r16;
                union { unsigned long long u; unsigned short s[4]; } pk;
                #pragma unroll
                for (int j = 0; j < 4; ++j) pk.s[j] = f2bf(acc[i][c][j]);
                *(unsigned long long*)&Vt[(((size_t)(bb * NH + h)) * HS + hs) * TT + tt0] = pk.u;
            }
        }
    }
}

// ---------------------------------------------------------------------------
// Kernel 3: out = Ob @ Wo + bo (fp32 out). (unchanged)
// ---------------------------------------------------------------------------
__global__ __launch_bounds__(256) void out_gemm_kernel(
    const unsigned short* __restrict__ Ob, const unsigned short* __restrict__ Wot,
    const float* __restrict__ bo, float* __restrict__ out)
{
    __shared__ __align__(16) unsigned short As2[128 * 32];
    __shared__ __align__(16) unsigned short Bs2[128 * 32];

    const int tid = threadIdx.x;
    const int l = tid & 63, w = tid >> 6;
    const int wr = w >> 1, wc = w & 1;
    const int g = l >> 4, r16 = l & 15;
    const int m0 = blockIdx.y * 128;
    const int n0 = blockIdx.x * 128;

    const unsigned short* aS[2]; unsigned short* aD[2];
    const unsigned short* bS[2]; unsigned short* bD[2];
    #pragma unroll
    for (int p = 0; p < 2; ++p) {
        int qid = p * 256 + tid;
        int row = qid >> 2, gl = qid & 3;
        int col = ((gl ^ ((row >> 1) & 3)) * 8);
        aS[p] = Ob + (size_t)(m0 + row) * DM + col;
        aD[p] = As2 + qid * 8;
        bS[p] = Wot + (size_t)(n0 + row) * DM + col;
        bD[p] = Bs2 + qid * 8;
    }

    int aoff[4], boff[4];
    #pragma unroll
    for (int i = 0; i < 4; ++i) {
        int row = wr * 64 + i * 16 + r16;
        aoff[i] = row * 32 + (g ^ ((row >> 1) & 3)) * 8;
    }
    #pragma unroll
    for (int c = 0; c < 4; ++c) {
        int row = wc * 64 + c * 16 + r16;
        boff[c] = row * 32 + (g ^ ((row >> 1) & 3)) * 8;
    }

    f32x4 acc[4][4];
    #pragma unroll
    for (int i = 0; i < 4; ++i)
        #pragma unroll
        for (int c = 0; c < 4; ++c)
            #pragma unroll
            for (int j = 0; j < 4; ++j) acc[i][c][j] = 0.0f;

    for (int k0 = 0; k0 < DM; k0 += 32) {
        #pragma unroll
        for (int p = 0; p < 2; ++p) gload16(aS[p] + k0, aD[p]);
        #pragma unroll
        for (int p = 0; p < 2; ++p) gload16(bS[p] + k0, bD[p]);
        __syncthreads();

        s16x8 af[4], bf[4];
        #pragma unroll
        for (int i = 0; i < 4; ++i) af[i] = *(const s16x8*)&As2[aoff[i]];
        #pragma unroll
        for (int c = 0; c < 4; ++c) bf[c] = *(const s16x8*)&Bs2[boff[c]];
        #pragma unroll
        for (int i = 0; i < 4; ++i)
            #pragma unroll
            for (int c = 0; c < 4; ++c)
                acc[i][c] = MFMA16(af[i], bf[c], acc[i][c]);
        __syncthreads();
    }

    #pragma unroll
    for (int i = 0; i < 4; ++i)
        #pragma unroll
        for (int j = 0; j < 4; ++j) {
            int row = m0 + wr * 64 + i * 16 + g * 4 + j;
            #pragma unroll
            for (int c = 0; c < 4; ++c) {
                int col = n0 + wc * 64 + c * 16 + r16;
                out[(size_t)row * DM + col] = acc[i][c][j] + bo[col];
            }
        }
}

// ---------------------------------------------------------------------------
// Kernel 2: causal flash attention v6 (unchanged from round 7).
// ---------------------------------------------------------------------------
template<bool MASKED>
__device__ __forceinline__ void ftile6(
    int kv0, int t0, int r16, int g,
    const unsigned short* __restrict__ Kl,
    const unsigned short* __restrict__ Vl,
    short* __restrict__ Pw,
    const s16x8 (&qf)[2],
    float (&l_part)[4], f32x4 (&o)[4])
{
    const int rs = r16 & 7;
    float pe[4][4];
    #pragma unroll
    for (int c = 0; c < 4; ++c) {
        if (!MASKED || (kv0 + c * 16 <= t0 + 15)) {
            f32x4 s0;
            #pragma unroll
            for (int j = 0; j < 4; ++j) s0[j] = 0.0f;
            const int base = (c * 16 + r16) * 64;
            s16x8 kf0 = *(const s16x8*)&Kl[base + ((g ^ rs) * 8)];
            s16x8 kf1 = *(const s16x8*)&Kl[base + (((4 + g) ^ rs) * 8)];
            s0 = MFMA16(qf[0], kf0, s0);
            s0 = MFMA16(qf[1], kf1, s0);
            #pragma unroll
            for (int j = 0; j < 4; ++j) {
                float e = __builtin_amdgcn_exp2f(s0[j] - 16.0f);
                if (MASKED)
                    e = (kv0 + c * 16 + r16 <= t0 + g * 4 + j) ? e : 0.0f;
                pe[c][j] = e;
                l_part[j] += e;
            }
        } else {
            #pragma unroll
            for (int j = 0; j < 4; ++j) pe[c][j] = 0.0f;
        }
    }

    #pragma unroll
    for (int c = 0; c < 2; ++c)
        #pragma unroll
        for (int j = 0; j < 4; ++j)
            Pw[(g * 4 + j) * 36 + c * 16 + r16] = (short)f2bfr(pe[c][j]);
    s16x8 pa0 = *(const s16x8*)&Pw[r16 * 36 + g * 8];
    #pragma unroll
    for (int c = 0; c < 4; ++c) {
        s16x8 vf = *(const s16x8*)&Vl[(c * 16 + r16) * 64 + ((g ^ rs) * 8)];
        o[c] = MFMA16(pa0, vf, o[c]);
    }

    if (!MASKED || (kv0 + 32 <= t0 + 15)) {
        #pragma unroll
        for (int c = 0; c < 2; ++c)
            #pragma unroll
            for (int j = 0; j < 4; ++j)
                Pw[(g * 4 + j) * 36 + c * 16 + r16] = (short)f2bfr(pe[2 + c][j]);
        s16x8 pa1 = *(const s16x8*)&Pw[r16 * 36 + g * 8];
        #pragma unroll
        for (int c = 0; c < 4; ++c) {
            s16x8 vf = *(const s16x8*)&Vl[(c * 16 + r16) * 64 + (((4 + g) ^ rs) * 8)];
            o[c] = MFMA16(pa1, vf, o[c]);
        }
    }
}

__global__ __launch_bounds__(256) void flash6_kernel(
    const unsigned short* __restrict__ Qb,
    const unsigned short* __restrict__ Kb,
    const unsigned short* __restrict__ Vt,
    unsigned short* __restrict__ Ob)
{
    __shared__ __align__(16) unsigned short Kls[2][4096];  // [64][64] x dbuf
    __shared__ __align__(16) unsigned short Vls[2][4096];
    __shared__ __align__(16) short Pl[4][576];             // per-wave [16][36]

    const int tid = threadIdx.x;
    const int l = tid & 63, w = tid >> 6;
    const int r16 = l & 15, g = l >> 4;

    const int bid = blockIdx.x;
    const int bh = bid & 31;
    const int jj = (bid >> 5) & 7;
    const int ii = bid >> 8;
    const int qc = ii * 8 + ((ii & 1) ? (7 - jj) : jj);
    const int numt = qc + 1;
    const int b = bh >> 4, h = bh & 15;

    const unsigned short* Qp = Qb + (size_t)bh * TT * HS;
    const unsigned short* Kp = Kb + (size_t)bh * TT * HS;
    const unsigned short* Vp = Vt + (size_t)bh * HS * TT;
    unsigned short* Op = Ob + (size_t)b * TT * DM + h * HS;
    short* Pw = Pl[w];

    const int t0 = qc * 64 + w * 16;

    const int srow0 = tid >> 3, c8 = tid & 7;
    const int srow1 = 32 + srow0;
    const unsigned short* kS0 = Kp + srow0 * HS + ((c8 ^ (srow0 & 7)) * 8);
    const unsigned short* kS1 = Kp + srow1 * HS + ((c8 ^ (srow1 & 7)) * 8);
    const unsigned short* vS0 = Vp + (size_t)srow0 * TT + ((c8 ^ (srow0 & 7)) * 8);
    const unsigned short* vS1 = Vp + (size_t)srow1 * TT + ((c8 ^ (srow1 & 7)) * 8);
    const int d0 = tid * 8, d1 = 2048 + tid * 8;

    s16x8 qf[2];
    #pragma unroll
    for (int s = 0; s < 2; ++s)
        qf[s] = *(const s16x8*)(Qp + (size_t)(t0 + r16) * HS + s * 32 + g * 8);

    float l_part[4] = {0.0f, 0.0f, 0.0f, 0.0f};
    f32x4 o[4];
    #pragma unroll
    for (int c = 0; c < 4; ++c)
        #pragma unroll
        for (int j = 0; j < 4; ++j) o[c][j] = 0.0f;

    #define STAGE(buf, kv0_) do {                                   \
        gload16(kS0 + (size_t)(kv0_) * HS, &Kls[(buf)][d0]);        \
        gload16(kS1 + (size_t)(kv0_) * HS, &Kls[(buf)][d1]);        \
        gload16(vS0 + (kv0_), &Vls[(buf)][d0]);                     \
        gload16(vS1 + (kv0_), &Vls[(buf)][d1]);                     \
    } while (0)

    STAGE(0, 0);
    for (int t = 0; t < numt - 1; ++t) {
        STAGE((t + 1) & 1, (t + 1) * 64);
        asm volatile("s_waitcnt vmcnt(4)" ::: "memory");
        __builtin_amdgcn_sched_barrier(0);
        __builtin_amdgcn_s_barrier();
        ftile6<false>(t * 64, t0, r16, g, &Kls[t & 1][0], &Vls[t & 1][0],
                      Pw, qf, l_part, o);
        __builtin_amdgcn_s_barrier();
    }
    asm volatile("s_waitcnt vmcnt(0)" ::: "memory");
    __builtin_amdgcn_sched_barrier(0);
    __builtin_amdgcn_s_barrier();
    ftile6<true>((numt - 1) * 64, t0, r16, g,
                 &Kls[(numt - 1) & 1][0], &Vls[(numt - 1) & 1][0],
                 Pw, qf, l_part, o);
    #undef STAGE

    #pragma unroll
    for (int j = 0; j < 4; ++j) {
        float ls = l_part[j];
        ls += __shfl_xor(ls, 1);
        ls += __shfl_xor(ls, 2);
        ls += __shfl_xor(ls, 4);
        ls += __shfl_xor(ls, 8);
        float inv = 1.0f / ls;
        int t = t0 + g * 4 + j;
        #pragma unroll
        for (int c = 0; c < 4; ++c)
            Op[(size_t)t * DM + c * 16 + r16] = f2bfr(o[c][j] * inv);
    }
}

// ---------------------------------------------------------------------------
extern "C" void kernel_launch(void* const* d_in, const int* in_sizes, int n_in,
                              void* d_out, int out_size, void* d_ws, size_t ws_size,
                              hipStream_t stream) {
    const float* q  = (const float*)d_in[0];
    const float* k  = (const float*)d_in[1];
    const float* v  = (const float*)d_in[2];
    const float* Wq = (const float*)d_in[3];
    const float* Wk = (const float*)d_in[4];
    const float* Wv = (const float*)d_in[5];
    const float* Wo = (const float*)d_in[6];
    const float* bo = (const float*)d_in[7];
    float* out = (float*)d_out;

    const size_t QKV_ELEMS = (size_t)BB * NH * TT * HS;  // 4 Mi elems (8 MB)
    unsigned short* Qb = (unsigned short*)d_ws;
    unsigned short* Kb = Qb + QKV_ELEMS;
    unsigned short* Vt = Kb + QKV_ELEMS;                 // [B,H,HS,T]
    unsigned short* R4 = Vt + QKV_ELEMS;                 // 8 MB shared region
    unsigned short* Wt = R4;                             // Wq/k/v^T (6 MB), pre-flash
    unsigned short* Ob = R4;                             // flash out, overwrites Wt
    unsigned short* Wot = Qb;                            // Wo^T (2 MB), post-flash

    cvt_w_kernel<<<dim3(16, 16, 3), 256, 0, stream>>>(Wq, Wk, Wv, Wt, 0);
    proj_gemm_kernel<<<dim3(768), 256, 0, stream>>>(q, k, v, Wt, Qb, Kb, Vt);
    flash6_kernel<<<dim3(1024), 256, 0, stream>>>(Qb, Kb, Vt, Ob);
    cvt_w_kernel<<<dim3(16, 16, 1), 256, 0, stream>>>(Wo, Wo, Wo, Wot, 1);
    out_gemm_kernel<<<dim3(8, 32), 256, 0, stream>>>(Ob, Wot, bo, out);
}